// Round 10
// baseline (1069.834 us; speedup 1.0000x reference)
//
#include <hip/hip_runtime.h>
#include <math.h>

// Problem constants (match reference)
#define NU_ 500000
#define NI_ 200000
#define NN_ 700000            // NU + NI
#define D_  64
#define E_  2000000
#define B_  131072
#define TWO_E 4000000
#define CAP_ 40               // bucket capacity; max deg ~30 (Poisson(10) tail), P(>40)~1e-12

typedef _Float16 half4 __attribute__((ext_vector_type(4)));  // 8 B
typedef _Float16 half8 __attribute__((ext_vector_type(8)));  // 16 B

// ---------------------------------------------------------------------------
// One-pass bucket CSR build. One endpoint per thread (2E threads).
// atomicAdd return IS the slot; atomicExch (not plain store) so the scattered
// 4B writes merge at the cache-side coherence point (R8 evidence: plain
// scattered stores emitted 247 MB write-through; atomicExch collapsed it).
// Bucket slot order is nondeterministic -> permutes fp summation only.
__global__ __launch_bounds__(256) void deg_fill_kernel(const int* __restrict__ eu,
                                                       const int* __restrict__ ei,
                                                       int* __restrict__ cnt,
                                                       int* __restrict__ adjb) {
    int t = blockIdx.x * 256 + threadIdx.x;   // t < 2E
    int e = t >> 1;
    int side = t & 1;
    int u = eu[e];
    int v = ei[e] + NU_;
    int node = side ? v : u;
    int nbr  = side ? u : v;
    int p = atomicAdd(&cnt[node], 1);
    if (p < CAP_) atomicExch(&adjb[(size_t)node * CAP_ + p], nbr);
}

__global__ __launch_bounds__(256) void inv_kernel(const int* __restrict__ cnt,
                                                  float* __restrict__ inv) {
    int v = blockIdx.x * 256 + threadIdx.x;
    if (v >= NN_) return;
    int d = cnt[v];
    inv[v] = (d > 0) ? (1.0f / sqrtf((float)d)) : 0.0f;
}

// ---------------------------------------------------------------------------
// Convert the concatenated [ue; ie] f32 embeddings to fp16 rows (128 B/row).
__global__ __launch_bounds__(256) void conv_kernel(const float* __restrict__ ue,
                                                   const float* __restrict__ ie,
                                                   half4* __restrict__ xh) {
    int t = blockIdx.x * 256 + threadIdx.x;
    int b = t >> 4;
    int q = t & 15;
    const float4* src = (b < NU_)
        ? ((const float4*)(ue + (size_t)b * D_) + q)
        : ((const float4*)(ie + (size_t)(b - NU_) * D_) + q);
    float4 a = *src;
    half4 h;
    h[0] = (_Float16)a.x; h[1] = (_Float16)a.y;
    h[2] = (_Float16)a.z; h[3] = (_Float16)a.w;
    xh[(size_t)b * 16 + q] = h;
}

// ---------------------------------------------------------------------------
// fp16 pull from fixed buckets (R8's proven single-batch loop):
// lane = g*8+q; g = neighbor slot (8), q = feature octet (16 B).
// out[v][:] = fp16( inv[v] * sum_n inv[n] * x[n][:] ), accumulation in f32.
__global__ __launch_bounds__(256) void pull_kernel(const _Float16* __restrict__ xhs,
                                                   const float* __restrict__ inv,
                                                   const int* __restrict__ cnt,
                                                   const int* __restrict__ adjb,
                                                   half8* __restrict__ out) {
    int t = blockIdx.x * 256 + threadIdx.x;
    int v = t >> 6;
    int lane = t & 63;
    int g = lane >> 3;        // neighbor slot (0..7)
    int q = lane & 7;         // feature octet (features 8q..8q+7)
    int deg = cnt[v];
    const int* bucket = adjb + (size_t)v * CAP_;
    float acc[8] = {0.f, 0.f, 0.f, 0.f, 0.f, 0.f, 0.f, 0.f};
    for (int s = 0; s < deg; s += 8) {
        int i = s + g;                        // <= 39, always inside bucket
        bool valid = i < deg;
        int n = bucket[i];                    // may be uninitialized past deg
        n = valid ? n : 0;                    // clamp BEFORE use as index
        float w = valid ? inv[n] : 0.0f;
        half8 a = *(const half8*)(xhs + ((unsigned)n * 64u + (unsigned)q * 8u));
#pragma unroll
        for (int k = 0; k < 8; ++k)
            acc[k] += w * (float)a[k];
    }
    // combine the 8 neighbor slots (g occupies lane bits 3..5)
#pragma unroll
    for (int k = 0; k < 8; ++k) {
        acc[k] += __shfl_xor(acc[k], 8);
        acc[k] += __shfl_xor(acc[k], 16);
        acc[k] += __shfl_xor(acc[k], 32);
    }
    if (g == 0) {
        float iv = inv[v];
        half8 o;
#pragma unroll
        for (int k = 0; k < 8; ++k) o[k] = (_Float16)(iv * acc[k]);
        out[(size_t)v * 8 + q] = o;
    }
}

// ---------------------------------------------------------------------------
// Per-node finalization: layer-3 pull from buckets + redistribute to
// lane-per-feature. Returns
//   Zfinal[lane] = emb[lane](f32) + x1[node][lane] + x2[node][lane] + inv*pull3.
__device__ __forceinline__ float node_final(int node,
                                            const float* __restrict__ embrow,
                                            const _Float16* __restrict__ x1,
                                            const _Float16* __restrict__ x2,
                                            const float* __restrict__ inv,
                                            const int* __restrict__ cnt,
                                            const int* __restrict__ adjb,
                                            int lane, int g, int q) {
    int deg = cnt[node];
    const int* bucket = adjb + (size_t)node * CAP_;
    float acc[8] = {0.f, 0.f, 0.f, 0.f, 0.f, 0.f, 0.f, 0.f};
    for (int s = 0; s < deg; s += 8) {
        int i = s + g;
        bool valid = i < deg;
        int n = bucket[i];
        n = valid ? n : 0;
        float w = valid ? inv[n] : 0.0f;
        half8 a = *(const half8*)(x2 + ((unsigned)n * 64u + (unsigned)q * 8u));
#pragma unroll
        for (int k = 0; k < 8; ++k)
            acc[k] += w * (float)a[k];
    }
#pragma unroll
    for (int k = 0; k < 8; ++k) {
        acc[k] += __shfl_xor(acc[k], 8);
        acc[k] += __shfl_xor(acc[k], 16);
        acc[k] += __shfl_xor(acc[k], 32);
    }
    // redistribute: lane wants feature `lane` = 8*(lane>>3) + (lane&7)
    float red = 0.0f;
#pragma unroll
    for (int k = 0; k < 8; ++k) {
        float tmp = __shfl(acc[k], lane >> 3);
        red = ((lane & 7) == k) ? tmp : red;
    }
    float e0 = embrow[lane];
    float l1 = (float)x1[(unsigned)node * 64u + (unsigned)lane];
    float l2 = (float)x2[(unsigned)node * 64u + (unsigned)lane];
    return e0 + l1 + l2 + inv[node] * red;
}

// ---------------------------------------------------------------------------
// Fully fused finalize + score: one wave per pair b. No Z buffers at all:
// Z = emb(f32 exact) + layer1(XAh) + layer2(XBh) + layer3(pulled here).
__global__ __launch_bounds__(256) void final_score_kernel(
        const float* __restrict__ ue,
        const float* __restrict__ ie,
        const _Float16* __restrict__ x1,      // layer-1 X (fp16)
        const _Float16* __restrict__ x2,      // layer-2 X (fp16)
        const float* __restrict__ inv,
        const int* __restrict__ cnt,
        const int* __restrict__ adjb,
        const int* __restrict__ users,
        const int* __restrict__ items,
        const float* __restrict__ fw,
        float* __restrict__ out) {
    int t = blockIdx.x * 256 + threadIdx.x;
    int b = t >> 6;
    int lane = t & 63;
    int g = lane >> 3;
    int q = lane & 7;

    int u  = users[b];
    int io = items[b];              // item index (0-based in ie)
    int it = io + NU_;              // item node id
    float zu = node_final(u,  ue + (size_t)u * D_,  x1, x2, inv, cnt, adjb, lane, g, q);
    float zi = node_final(it, ie + (size_t)io * D_, x1, x2, inv, cnt, adjb, lane, g, q);

    // score: s = sum_{f,gg} fw[f,gg] * dot(zu[f*16: ], zi[gg*16: ])
    int f = lane >> 4;
    float s = 0.0f;
#pragma unroll
    for (int gg = 0; gg < 4; ++gg) {
        float pi = __shfl(zi, (gg << 4) | (lane & 15));
        float p = zu * pi;
        p += __shfl_xor(p, 1);
        p += __shfl_xor(p, 2);
        p += __shfl_xor(p, 4);
        p += __shfl_xor(p, 8);
        s += fw[f * 4 + gg] * p;
    }
    s += __shfl_xor(s, 16);
    s += __shfl_xor(s, 32);
    if (lane == 0) out[b] = s * 0.0625f;  // (1/4)*(1/4) layer-mean scaling
}

// ---------------------------------------------------------------------------
extern "C" void kernel_launch(void* const* d_in, const int* in_sizes, int n_in,
                              void* d_out, int out_size, void* d_ws, size_t ws_size,
                              hipStream_t stream) {
    const float* ue    = (const float*)d_in[0];  // [NU, 64]
    const float* ie    = (const float*)d_in[1];  // [NI, 64]
    const float* fw    = (const float*)d_in[2];  // [4, 4]
    const int*   eu    = (const int*)d_in[3];    // [E]
    const int*   eitem = (const int*)d_in[4];    // [E]
    const int*   users = (const int*)d_in[5];    // [B]
    const int*   items = (const int*)d_in[6];    // [B]
    float* scores = (float*)d_out;               // [B]

    const size_t xh_bytes = (size_t)NN_ * D_ * 2;             // 89.6 MB (fp16)

    char* ws = (char*)d_ws;
    half8* X0h  = (half8*)ws;  ws += xh_bytes;   // layer-0; reused as layer-2 out
    half8* XAh  = (half8*)ws;  ws += xh_bytes;   // layer-1
    float* inv  = (float*)ws;  ws += (size_t)NN_ * 4;
    int*   cnt  = (int*)ws;    ws += (size_t)NN_ * 4;
    int*   adjb = (int*)ws;    ws += (size_t)NN_ * CAP_ * 4;  // 112 MB buckets
    half8* XBh  = X0h;         // ping-pong: X0h dead after layer-1 pull

    // --- one-pass bucket CSR build (atomicAdd slot + atomicExch store) --
    hipMemsetAsync(cnt, 0, (size_t)NN_ * 4, stream);
    deg_fill_kernel<<<TWO_E / 256, 256, 0, stream>>>(eu, eitem, cnt, adjb);
    inv_kernel<<<(NN_ + 255) / 256, 256, 0, stream>>>(cnt, inv);

    // --- fp16 conversion of layer-0 X ----------------------------------
    conv_kernel<<<(NN_ * 16) / 256, 256, 0, stream>>>(ue, ie, (half4*)X0h);

    // --- propagation ----------------------------------------------------
    pull_kernel<<<(NN_ * D_) / 256, 256, 0, stream>>>(
        (const _Float16*)X0h, inv, cnt, adjb, XAh);
    pull_kernel<<<(NN_ * D_) / 256, 256, 0, stream>>>(
        (const _Float16*)XAh, inv, cnt, adjb, XBh);

    // --- fused finalize (emb + l1 + l2 + l3-pull) + score ---------------
    final_score_kernel<<<(B_ * D_) / 256, 256, 0, stream>>>(
        ue, ie, (const _Float16*)XAh, (const _Float16*)XBh,
        inv, cnt, adjb, users, items, fw, scores);
}